// Round 1
// baseline (196.250 us; speedup 1.0000x reference)
//
#include <hip/hip_runtime.h>
#include <hip/hip_bf16.h>

typedef __bf16 bf16x8 __attribute__((ext_vector_type(8)));
typedef float  f32x4  __attribute__((ext_vector_type(4)));

#define MFMA16(a, b, c) __builtin_amdgcn_mfma_f32_16x16x32_bf16((a), (b), (c), 0, 0, 0)

// Problem constants
// BS=4, C=128, L=H*W=4096, D=INNER=64, scale = 1/8 exactly.

// ---------------------------------------------------------------------------
// Kernel 1: QKV projection.  x[b,l,c] = inpt[b,c,l].
// Q/K stored bf16 [b][l][64]; V stored bf16 TRANSPOSED [b][d][4096].
// Block: 64 tokens, 256 threads = 4 tokens x 12 outputs per thread (192 outs).
// ---------------------------------------------------------------------------
__global__ __launch_bounds__(256) void qkv_kernel(
    const float* __restrict__ inpt,
    const float* __restrict__ Wq, const float* __restrict__ bq,
    const float* __restrict__ Wk, const float* __restrict__ bk,
    const float* __restrict__ Wv, const float* __restrict__ bv,
    __bf16* __restrict__ Qws, __bf16* __restrict__ Kws, __bf16* __restrict__ VTws)
{
    __shared__ __align__(16) float xs[128 * 68];   // [c][token], pad 68
    const int bid = blockIdx.x;                    // 0..255
    const int b  = bid >> 6;
    const int l0 = (bid & 63) << 6;
    const int t  = threadIdx.x;

    // stage x tile: 128 c x 64 tokens (coalesced: rows of inpt are l-contig)
    const float* xin = inpt + ((size_t)b * 128) * 4096 + l0;
    #pragma unroll
    for (int i = 0; i < 8; ++i) {
        int fl4 = t + 256 * i;                     // 0..2047 float4 chunks
        int c = fl4 >> 4, t4 = (fl4 & 15) << 2;
        float4 v = *(const float4*)(xin + c * 4096 + t4);
        *(float4*)&xs[c * 68 + t4] = v;
    }
    __syncthreads();

    const int tg = t & 15, og = t >> 4;
    const int t0 = tg << 2;        // 4 tokens
    const int o0 = og * 12;        // 12 of 192 outputs (0-63 q, 64-127 k, 128-191 v)

    float acc[12][4];
    #pragma unroll
    for (int j = 0; j < 12; ++j)
        #pragma unroll
        for (int i = 0; i < 4; ++i) acc[j][i] = 0.f;

    const float* wrow[12];
    #pragma unroll
    for (int j = 0; j < 12; ++j) {
        int o = o0 + j, mat = o >> 6, d = o & 63;
        const float* W = (mat == 0) ? Wq : ((mat == 1) ? Wk : Wv);
        wrow[j] = W + d * 128;
    }

    for (int c0 = 0; c0 < 128; c0 += 4) {
        float xtf[4][4];
        #pragma unroll
        for (int ci = 0; ci < 4; ++ci) {
            float4 v = *(const float4*)&xs[(c0 + ci) * 68 + t0];
            xtf[ci][0] = v.x; xtf[ci][1] = v.y; xtf[ci][2] = v.z; xtf[ci][3] = v.w;
        }
        #pragma unroll
        for (int j = 0; j < 12; ++j) {
            float4 w4 = *(const float4*)(wrow[j] + c0);   // L1/L2 broadcast
            #pragma unroll
            for (int i = 0; i < 4; ++i)
                acc[j][i] += xtf[0][i] * w4.x + xtf[1][i] * w4.y
                           + xtf[2][i] * w4.z + xtf[3][i] * w4.w;
        }
    }

    // bias + store
    #pragma unroll
    for (int j = 0; j < 12; ++j) {
        int o = o0 + j, mat = o >> 6, d = o & 63;
        const float* bias = (mat == 0) ? bq : ((mat == 1) ? bk : bv);
        float bv_ = bias[d];
        if (mat < 2) {
            __bf16* dst = ((mat == 0) ? Qws : Kws)
                        + (((size_t)b << 12) + l0 + t0) * 64 + d;
            #pragma unroll
            for (int i = 0; i < 4; ++i) dst[(size_t)i * 64] = (__bf16)(acc[j][i] + bv_);
        } else {
            __bf16* dst = VTws + (((size_t)b << 6) + d) * 4096 + l0 + t0;
            #pragma unroll
            for (int i = 0; i < 4; ++i) dst[i] = (__bf16)(acc[j][i] + bv_);
        }
    }
}

// ---------------------------------------------------------------------------
// Kernel 2: flash attention, bf16 MFMA 16x16x32.
// Block: 64 queries (wave w owns q-rows 16w..16w+15), K-tile = 64 keys.
// Verified layouts: A/B frag: [m|n = lane&15][k = quad*8+j]; C/D: col=lane&15,
// row = quad*4 + reg.  P round-trips through LDS to reach A-operand layout.
// ---------------------------------------------------------------------------
__global__ __launch_bounds__(256) void attn_kernel(
    const __bf16* __restrict__ Qws, const __bf16* __restrict__ Kws,
    const __bf16* __restrict__ VTws, float* __restrict__ ctxws)
{
    __shared__ __align__(16) __bf16 kb[64 * 72];        // [key][d]   stride 72
    __shared__ __align__(16) __bf16 vT[64 * 72];        // [d][key]   stride 72
    __shared__ __align__(16) float  sS[4 * 16 * 68];    // per-wave [q][k] fp32
    __shared__ __align__(16) __bf16 pB[4 * 16 * 72];    // per-wave P bf16 [q][k]
    __shared__ float mL[64], lL[64], af[64];

    const int bid  = blockIdx.x;
    const int b    = bid >> 6;
    const int l0   = (bid & 63) << 6;
    const int t    = threadIdx.x;
    const int w    = t >> 6;
    const int lane = t & 63;
    const int quad = lane >> 4;
    const int l15  = lane & 15;

    if (t < 64) { mL[t] = -1e30f; lL[t] = 0.f; }

    float*  sSw = sS + w * (16 * 68);
    __bf16* pBw = pB + w * (16 * 72);
    float*  mLw = mL + w * 16;
    float*  lLw = lL + w * 16;
    float*  afw = af + w * 16;

    // Q fragments: fixed for whole K loop (row = l15 within wave's 16 rows)
    const __bf16* qptr = Qws + ((((size_t)b << 12) + l0 + w * 16 + l15) << 6) + quad * 8;
    bf16x8 qf0 = *(const bf16x8*)qptr;
    bf16x8 qf1 = *(const bf16x8*)(qptr + 32);

    f32x4 cfr[4];
    #pragma unroll
    for (int nt = 0; nt < 4; ++nt)
        #pragma unroll
        for (int rr = 0; rr < 4; ++rr) cfr[nt][rr] = 0.f;

    const uint4* Kg = (const uint4*)(Kws + (((size_t)b << 12) << 6));
    const uint4* Vg = (const uint4*)(VTws + ((size_t)b << 6) * 4096);

    for (int kt = 0; kt < 64; ++kt) {
        const int kk0 = kt << 6;
        // stage K tile: 64 keys x 64 d, 16B chunks
        #pragma unroll
        for (int i = 0; i < 2; ++i) {
            int fl = t + (i << 8);               // 0..511
            int key = fl >> 3, d8 = fl & 7;
            uint4 val = Kg[((kk0 + key) << 3) + d8];
            *(uint4*)&kb[key * 72 + (d8 << 3)] = val;
        }
        // stage V tile (already transposed in ws): 64 d x 64 keys
        #pragma unroll
        for (int i = 0; i < 2; ++i) {
            int fl = t + (i << 8);
            int d = fl >> 3, k8 = fl & 7;
            uint4 val = Vg[(d << 9) + (kk0 >> 3) + k8];
            *(uint4*)&vT[d * 72 + (k8 << 3)] = val;
        }
        __syncthreads();

        // ---- QK^T: S[16 q][64 k] per wave ----
        #pragma unroll
        for (int nt = 0; nt < 4; ++nt) {
            const __bf16* kp = &kb[(nt * 16 + l15) * 72 + quad * 8];
            bf16x8 kf0 = *(const bf16x8*)kp;
            bf16x8 kf1 = *(const bf16x8*)(kp + 32);
            f32x4 s = {0.f, 0.f, 0.f, 0.f};
            s = MFMA16(qf0, kf0, s);
            s = MFMA16(qf1, kf1, s);
            #pragma unroll
            for (int r = 0; r < 4; ++r)
                sSw[(quad * 4 + r) * 68 + nt * 16 + l15] = s[r] * 0.125f;
        }

        // ---- online softmax (wave-private rows; lane = row*4 + quarter) ----
        {
            const int r = lane >> 2, qc = lane & 3;
            const float* srow = &sSw[r * 68 + qc * 16];
            float sv[16];
            float mloc = -1e30f;
            #pragma unroll
            for (int j = 0; j < 16; ++j) { sv[j] = srow[j]; mloc = fmaxf(mloc, sv[j]); }
            mloc = fmaxf(mloc, __shfl_xor(mloc, 1));
            mloc = fmaxf(mloc, __shfl_xor(mloc, 2));
            float mold = mLw[r];
            float mnew = fmaxf(mold, mloc);
            float alpha = __expf(mold - mnew);
            float lsum = 0.f;
            __bf16* prow = &pBw[r * 72 + qc * 16];
            #pragma unroll
            for (int j = 0; j < 16; ++j) {
                float p = __expf(sv[j] - mnew);
                prow[j] = (__bf16)p;
                lsum += p;
            }
            lsum += __shfl_xor(lsum, 1);
            lsum += __shfl_xor(lsum, 2);
            if (qc == 0) { mLw[r] = mnew; lLw[r] = lLw[r] * alpha + lsum; afw[r] = alpha; }
        }

        // ---- PV: ctx = ctx*alpha + P·V ----
        float ar[4];
        #pragma unroll
        for (int rr = 0; rr < 4; ++rr) ar[rr] = afw[quad * 4 + rr];
        #pragma unroll
        for (int nt = 0; nt < 4; ++nt)
            #pragma unroll
            for (int rr = 0; rr < 4; ++rr) cfr[nt][rr] *= ar[rr];

        bf16x8 pa0 = *(const bf16x8*)&pBw[l15 * 72 + quad * 8];
        bf16x8 pa1 = *(const bf16x8*)&pBw[l15 * 72 + 32 + quad * 8];
        #pragma unroll
        for (int nt = 0; nt < 4; ++nt) {
            const __bf16* vp = &vT[(nt * 16 + l15) * 72 + quad * 8];
            bf16x8 vf0 = *(const bf16x8*)vp;
            bf16x8 vf1 = *(const bf16x8*)(vp + 32);
            cfr[nt] = MFMA16(pa0, vf0, cfr[nt]);
            cfr[nt] = MFMA16(pa1, vf1, cfr[nt]);
        }
        __syncthreads();   // protect kb/vT for next tile's staging
    }

    // epilogue: divide by l, store ctx fp32 [b][l][64]
    float linv[4];
    #pragma unroll
    for (int rr = 0; rr < 4; ++rr) linv[rr] = 1.0f / lLw[quad * 4 + rr];
    float* obase = ctxws + ((((size_t)b << 12) + l0 + w * 16 + quad * 4) << 6) + l15;
    #pragma unroll
    for (int nt = 0; nt < 4; ++nt)
        #pragma unroll
        for (int rr = 0; rr < 4; ++rr)
            obase[(size_t)rr * 64 + nt * 16] = cfr[nt][rr] * linv[rr];
}

// ---------------------------------------------------------------------------
// Kernel 3: output projection + bias + residual.
// out[b,c,l] = inpt[b,c,l] + bo[c] + sum_d ctx[b,l,d] * Wo[c,d]
// ---------------------------------------------------------------------------
__global__ __launch_bounds__(256) void outproj_kernel(
    const float* __restrict__ inpt, const float* __restrict__ ctxws,
    const float* __restrict__ Wo, const float* __restrict__ bo,
    float* __restrict__ out)
{
    __shared__ __align__(16) float cxT[64 * 68];   // [d][token]
    const int bid = blockIdx.x;
    const int b  = bid >> 6;
    const int l0 = (bid & 63) << 6;
    const int t  = threadIdx.x;

    const float* cbase = ctxws + ((((size_t)b << 12) + l0) << 6);
    #pragma unroll
    for (int i = 0; i < 4; ++i) {
        int fl4 = t + 256 * i;                    // 0..1023
        int tok = fl4 >> 4, d4 = (fl4 & 15) << 2;
        float4 v = *(const float4*)(cbase + tok * 64 + d4);
        cxT[(d4 + 0) * 68 + tok] = v.x;
        cxT[(d4 + 1) * 68 + tok] = v.y;
        cxT[(d4 + 2) * 68 + tok] = v.z;
        cxT[(d4 + 3) * 68 + tok] = v.w;
    }
    __syncthreads();

    const int tg = t & 15, cg = t >> 4;
    const int t0 = tg << 2;       // 4 tokens
    const int c0 = cg * 8;        // 8 channels

    float acc[8][4];
    #pragma unroll
    for (int j = 0; j < 8; ++j)
        #pragma unroll
        for (int i = 0; i < 4; ++i) acc[j][i] = 0.f;

    for (int d0 = 0; d0 < 64; d0 += 4) {
        float xtf[4][4];
        #pragma unroll
        for (int di = 0; di < 4; ++di) {
            float4 v = *(const float4*)&cxT[(d0 + di) * 68 + t0];
            xtf[di][0] = v.x; xtf[di][1] = v.y; xtf[di][2] = v.z; xtf[di][3] = v.w;
        }
        #pragma unroll
        for (int j = 0; j < 8; ++j) {
            float4 w4 = *(const float4*)(Wo + (c0 + j) * 64 + d0);
            #pragma unroll
            for (int i = 0; i < 4; ++i)
                acc[j][i] += xtf[0][i] * w4.x + xtf[1][i] * w4.y
                           + xtf[2][i] * w4.z + xtf[3][i] * w4.w;
        }
    }

    #pragma unroll
    for (int j = 0; j < 8; ++j) {
        int c = c0 + j;
        float bias = bo[c];
        const float* ip = inpt + (((size_t)b << 7) + c) * 4096 + l0 + t0;
        float*       op = out  + (((size_t)b << 7) + c) * 4096 + l0 + t0;
        float4 iv = *(const float4*)ip;
        float4 ov;
        ov.x = iv.x + acc[j][0] + bias;
        ov.y = iv.y + acc[j][1] + bias;
        ov.z = iv.z + acc[j][2] + bias;
        ov.w = iv.w + acc[j][3] + bias;
        *(float4*)op = ov;
    }
}

// ---------------------------------------------------------------------------
extern "C" void kernel_launch(void* const* d_in, const int* in_sizes, int n_in,
                              void* d_out, int out_size, void* d_ws, size_t ws_size,
                              hipStream_t stream)
{
    const float* inpt = (const float*)d_in[0];
    const float* Wq   = (const float*)d_in[1];
    const float* bq   = (const float*)d_in[2];
    const float* Wk   = (const float*)d_in[3];
    const float* bk   = (const float*)d_in[4];
    const float* Wv   = (const float*)d_in[5];
    const float* bv   = (const float*)d_in[6];
    const float* Wo   = (const float*)d_in[7];
    const float* bo   = (const float*)d_in[8];
    float* out = (float*)d_out;

    char* ws = (char*)d_ws;
    const size_t SEG = (size_t)1 << 21;            // 2 MiB per bf16 tensor (4*4096*64*2B)
    __bf16* Qws  = (__bf16*)(ws + 0 * SEG);
    __bf16* Kws  = (__bf16*)(ws + 1 * SEG);
    __bf16* VTws = (__bf16*)(ws + 2 * SEG);        // transposed [b][d][l]
    float*  ctxws = (float*)(ws + 3 * SEG);        // fp32 [b][l][64], 4 MiB

    qkv_kernel<<<256, 256, 0, stream>>>(inpt, Wq, bq, Wk, bk, Wv, bv, Qws, Kws, VTws);
    attn_kernel<<<256, 256, 0, stream>>>(Qws, Kws, VTws, ctxws);
    outproj_kernel<<<256, 256, 0, stream>>>(inpt, ctxws, Wo, bo, out);
}

// Round 2
// 151.297 us; speedup vs baseline: 1.2971x; 1.2971x over previous
//
#include <hip/hip_runtime.h>
#include <hip/hip_bf16.h>

typedef __bf16 bf16x8 __attribute__((ext_vector_type(8)));
typedef __bf16 bf16x4 __attribute__((ext_vector_type(4)));
typedef float  f32x4  __attribute__((ext_vector_type(4)));

#define MFMA16(a, b, c) __builtin_amdgcn_mfma_f32_16x16x32_bf16((a), (b), (c), 0, 0, 0)

#define SPLIT 4   // k-dim splits in attention (64 k-tiles / 16 per block)

// BS=4, C=128, L=4096, D=64, scale folded into Q (1/8).

// ---------------------------------------------------------------------------
// Kernel 1: QKV projection. grid = 3 x 256: z picks Wq/Wk/Wv, tile picks
// (b, 64-token slab). 3 blocks/CU. Q pre-scaled by 1/8.
// Q/K bf16 [b][l][64]; V bf16 transposed [b][d][4096].
// ---------------------------------------------------------------------------
__global__ __launch_bounds__(256) void qkv_kernel(
    const float* __restrict__ inpt,
    const float* __restrict__ Wq, const float* __restrict__ bq,
    const float* __restrict__ Wk, const float* __restrict__ bk,
    const float* __restrict__ Wv, const float* __restrict__ bv,
    __bf16* __restrict__ Qws, __bf16* __restrict__ Kws, __bf16* __restrict__ VTws)
{
    __shared__ __align__(16) float xs[128 * 68];   // [c][token]
    const int bid  = blockIdx.x;
    const int z    = bid >> 8;                     // 0=Q 1=K 2=V
    const int tile = bid & 255;
    const int b  = tile >> 6;
    const int l0 = (tile & 63) << 6;
    const int t  = threadIdx.x;

    const float* xin = inpt + ((size_t)b * 128) * 4096 + l0;
    #pragma unroll
    for (int i = 0; i < 8; ++i) {
        int fl4 = t + 256 * i;                     // 2048 float4 chunks
        int c = fl4 >> 4, t4 = (fl4 & 15) << 2;
        *(float4*)&xs[c * 68 + t4] = *(const float4*)(xin + c * 4096 + t4);
    }
    __syncthreads();

    const float* W  = (z == 0) ? Wq : ((z == 1) ? Wk : Wv);
    const float* bb = (z == 0) ? bq : ((z == 1) ? bk : bv);
    const float scl = (z == 0) ? 0.125f : 1.0f;

    const int tg = t & 15, og = t >> 4;
    const int t0 = tg << 2;      // 4 tokens
    const int o0 = og << 2;      // 4 outputs (of 64)

    float acc[4][4];             // [out][tok]
    #pragma unroll
    for (int j = 0; j < 4; ++j)
        #pragma unroll
        for (int i = 0; i < 4; ++i) acc[j][i] = 0.f;

    for (int c0 = 0; c0 < 128; c0 += 4) {
        float xt[4][4];
        #pragma unroll
        for (int ci = 0; ci < 4; ++ci) {
            float4 v = *(const float4*)&xs[(c0 + ci) * 68 + t0];
            xt[ci][0] = v.x; xt[ci][1] = v.y; xt[ci][2] = v.z; xt[ci][3] = v.w;
        }
        #pragma unroll
        for (int j = 0; j < 4; ++j) {
            float4 w4 = *(const float4*)(W + (o0 + j) * 128 + c0);
            #pragma unroll
            for (int i = 0; i < 4; ++i)
                acc[j][i] += xt[0][i] * w4.x + xt[1][i] * w4.y
                           + xt[2][i] * w4.z + xt[3][i] * w4.w;
        }
    }

    if (z < 2) {
        __bf16* base = (z == 0) ? Qws : Kws;
        #pragma unroll
        for (int i = 0; i < 4; ++i) {
            bf16x4 v;
            #pragma unroll
            for (int j = 0; j < 4; ++j)
                v[j] = (__bf16)((acc[j][i] + bb[o0 + j]) * scl);
            *(bf16x4*)(base + (((size_t)b << 12) + l0 + t0 + i) * 64 + o0) = v;
        }
    } else {
        #pragma unroll
        for (int j = 0; j < 4; ++j) {
            bf16x4 v;
            float bj = bb[o0 + j];
            #pragma unroll
            for (int i = 0; i < 4; ++i) v[i] = (__bf16)(acc[j][i] + bj);
            *(bf16x4*)(VTws + ((size_t)(b * 64 + o0 + j)) * 4096 + l0 + t0) = v;
        }
    }
}

// ---------------------------------------------------------------------------
// Kernel 2: flash attention, split-K, in-register softmax.
// grid = SPLIT x 256. Block: 64 q (wave w owns 16), 16 k-tiles of 64 keys.
// S^T trick: MFMA(A=K, B=Q) -> lane l15 holds ALL its q's stats; m/l/alpha in
// registers; P transposed to B-frag layout via 16 shuffles (no LDS for S/P).
// Partial O (unnormalized), m, l written per split; combined in outproj.
// ---------------------------------------------------------------------------
__global__ __launch_bounds__(256, 4) void attn_kernel(
    const __bf16* __restrict__ Qws, const __bf16* __restrict__ Kws,
    const __bf16* __restrict__ VTws,
    float* __restrict__ Ops, float* __restrict__ Mws, float* __restrict__ Lws)
{
    __shared__ __align__(16) __bf16 kb[64 * 72];   // [key][d]
    __shared__ __align__(16) __bf16 vT[64 * 72];   // [d][key]

    const int bid   = blockIdx.x;
    const int split = bid >> 8;
    const int qt    = bid & 255;
    const int b  = qt >> 6;
    const int l0 = (qt & 63) << 6;
    const int t    = threadIdx.x;
    const int w    = t >> 6;
    const int lane = t & 63;
    const int quad = lane >> 4;
    const int l15  = lane & 15;

    // Q fragments (q = l15 within wave tile), pre-scaled by 1/8
    const __bf16* qptr = Qws + (((size_t)b << 12) + l0 + w * 16 + l15) * 64 + quad * 8;
    bf16x8 qf0 = *(const bf16x8*)qptr;
    bf16x8 qf1 = *(const bf16x8*)(qptr + 32);

    f32x4 cfr[4];                                  // ctx^T: [d-tile nt][r], q=l15
    #pragma unroll
    for (int nt = 0; nt < 4; ++nt)
        #pragma unroll
        for (int r = 0; r < 4; ++r) cfr[nt][r] = 0.f;
    float m_run = -1e30f, l_run = 0.f;             // replicated across 4 quads

    const uint4* Kg = (const uint4*)(Kws + (((size_t)b << 12)) * 64);
    const uint4* Vg = (const uint4*)(VTws + ((size_t)(b * 64)) * 4096);

    const int  sA = ((quad << 1) & 3) * 16 + l15;        // shuffle source lanes
    const int  sB = (((quad << 1) | 1) & 3) * 16 + l15;
    const bool hi = (quad & 2) != 0;                      // nt select: quad>>1

    union U8 { uint4 u; bf16x8 v; };
    union P4 { bf16x4 v; uint2 u; };

    for (int kt = split * 16; kt < split * 16 + 16; ++kt) {
        const int kk0 = kt << 6;
        #pragma unroll
        for (int i = 0; i < 2; ++i) {
            int fl = t + (i << 8);                 // 0..511
            int r8 = fl >> 3, c8 = fl & 7;
            *(uint4*)&kb[r8 * 72 + (c8 << 3)] = Kg[(size_t)(kk0 + r8) * 8 + c8];
            *(uint4*)&vT[r8 * 72 + (c8 << 3)] = Vg[(size_t)r8 * 512 + (kk0 >> 3) + c8];
        }
        __syncthreads();

        // ---- S^T = K·Q^T : s[nt][r] = score(q=l15, k=nt*16+quad*4+r) ----
        f32x4 s[4];
        #pragma unroll
        for (int nt = 0; nt < 4; ++nt) {
            const __bf16* kp = &kb[(nt * 16 + l15) * 72 + quad * 8];
            bf16x8 kf0 = *(const bf16x8*)kp;
            bf16x8 kf1 = *(const bf16x8*)(kp + 32);
            f32x4 a = {0.f, 0.f, 0.f, 0.f};
            a = MFMA16(kf0, qf0, a);
            a = MFMA16(kf1, qf1, a);
            s[nt] = a;
        }

        // ---- online softmax, all in registers ----
        float mx = -1e30f;
        #pragma unroll
        for (int nt = 0; nt < 4; ++nt)
            #pragma unroll
            for (int r = 0; r < 4; ++r) mx = fmaxf(mx, s[nt][r]);
        mx = fmaxf(mx, __shfl_xor(mx, 16));
        mx = fmaxf(mx, __shfl_xor(mx, 32));
        float mnew  = fmaxf(m_run, mx);
        float alpha = __expf(m_run - mnew);
        m_run = mnew;

        float psum = 0.f;
        uint2 pk[4];
        #pragma unroll
        for (int nt = 0; nt < 4; ++nt) {
            P4 pp;
            #pragma unroll
            for (int r = 0; r < 4; ++r) {
                float p = __expf(s[nt][r] - mnew);
                psum += p;
                pp.v[r] = (__bf16)p;
            }
            pk[nt] = pp.u;
        }
        psum += __shfl_xor(psum, 16);
        psum += __shfl_xor(psum, 32);
        l_run = l_run * alpha + psum;

        // ---- transpose P (C-layout) -> B-frag layout via shuffles ----
        int a0x = __shfl((int)pk[0].x, sA), a0y = __shfl((int)pk[0].y, sA);
        int a1x = __shfl((int)pk[1].x, sA), a1y = __shfl((int)pk[1].y, sA);
        int a2x = __shfl((int)pk[2].x, sA), a2y = __shfl((int)pk[2].y, sA);
        int a3x = __shfl((int)pk[3].x, sA), a3y = __shfl((int)pk[3].y, sA);
        int b0x = __shfl((int)pk[0].x, sB), b0y = __shfl((int)pk[0].y, sB);
        int b1x = __shfl((int)pk[1].x, sB), b1y = __shfl((int)pk[1].y, sB);
        int b2x = __shfl((int)pk[2].x, sB), b2y = __shfl((int)pk[2].y, sB);
        int b3x = __shfl((int)pk[3].x, sB), b3y = __shfl((int)pk[3].y, sB);
        U8 c0u, c1u;
        c0u.u.x = hi ? (uint)a1x : (uint)a0x;  c0u.u.y = hi ? (uint)a1y : (uint)a0y;
        c0u.u.z = hi ? (uint)b1x : (uint)b0x;  c0u.u.w = hi ? (uint)b1y : (uint)b0y;
        c1u.u.x = hi ? (uint)a3x : (uint)a2x;  c1u.u.y = hi ? (uint)a3y : (uint)a2y;
        c1u.u.z = hi ? (uint)b3x : (uint)b2x;  c1u.u.w = hi ? (uint)b3y : (uint)b2y;
        bf16x8 pb0 = c0u.v;   // P[q=l15][k=quad*8+j], keys 0..31
        bf16x8 pb1 = c1u.v;   // keys 32..63

        // ---- ctx^T = ctx^T*alpha + V^T·P^T ----
        #pragma unroll
        for (int nt = 0; nt < 4; ++nt)
            #pragma unroll
            for (int r = 0; r < 4; ++r) cfr[nt][r] *= alpha;
        #pragma unroll
        for (int nt = 0; nt < 4; ++nt) {
            const __bf16* vp = &vT[(nt * 16 + l15) * 72 + quad * 8];
            bf16x8 vf0 = *(const bf16x8*)vp;
            bf16x8 vf1 = *(const bf16x8*)(vp + 32);
            cfr[nt] = MFMA16(vf0, pb0, cfr[nt]);
            cfr[nt] = MFMA16(vf1, pb1, cfr[nt]);
        }
        __syncthreads();
    }

    // epilogue: unnormalized partial ctx + (m,l) per split
    const int l = l0 + w * 16 + l15;
    const int row = (split * 4 + b) * 4096 + l;
    float* obase = Ops + (size_t)row * 64;
    #pragma unroll
    for (int nt = 0; nt < 4; ++nt)
        *(f32x4*)(obase + nt * 16 + quad * 4) = cfr[nt];
    if (quad == 0) { Mws[row] = m_run; Lws[row] = l_run; }
}

// ---------------------------------------------------------------------------
// Kernel 3: split-combine + output projection + bias + residual.
// grid = 1024: (b, 32-token slab) x channel-half. 4 blocks/CU.
// ---------------------------------------------------------------------------
__global__ __launch_bounds__(256) void outproj_kernel(
    const float* __restrict__ inpt,
    const float* __restrict__ Ops, const float* __restrict__ Mws,
    const float* __restrict__ Lws,
    const float* __restrict__ Wo, const float* __restrict__ bo,
    float* __restrict__ out)
{
    __shared__ __align__(16) float cx[32 * 68];    // combined ctx [tok][d]
    __shared__ float wspl[SPLIT * 32];             // per-token split weights

    const int bid  = blockIdx.x;
    const int h    = bid & 1;                      // channel half
    const int tile = bid >> 1;
    const int b  = tile >> 7;
    const int l0 = (tile & 127) << 5;              // 32-token slab
    const int t  = threadIdx.x;

    if (t < 32) {
        const int l = l0 + t;
        float m[SPLIT], ls[SPLIT];
        float mmax = -1e30f;
        #pragma unroll
        for (int s = 0; s < SPLIT; ++s) {
            int idx = (s * 4 + b) * 4096 + l;
            m[s] = Mws[idx]; ls[s] = Lws[idx];
            mmax = fmaxf(mmax, m[s]);
        }
        float Lt = 0.f, e[SPLIT];
        #pragma unroll
        for (int s = 0; s < SPLIT; ++s) { e[s] = __expf(m[s] - mmax); Lt += ls[s] * e[s]; }
        float inv = 1.f / Lt;
        #pragma unroll
        for (int s = 0; s < SPLIT; ++s) wspl[s * 32 + t] = e[s] * inv;
    }
    __syncthreads();

    // combine splits while staging ctx into LDS (coalesced float4)
    #pragma unroll
    for (int i = 0; i < 2; ++i) {
        int ch  = t + (i << 8);                    // 512 chunks
        int tok = ch >> 4, d4 = (ch & 15) << 2;
        float ax = 0.f, ay = 0.f, az = 0.f, aw = 0.f;
        #pragma unroll
        for (int s = 0; s < SPLIT; ++s) {
            const float4 v = *(const float4*)(Ops
                + ((size_t)((s * 4 + b) * 4096 + l0 + tok)) * 64 + d4);
            float ww = wspl[s * 32 + tok];
            ax += ww * v.x; ay += ww * v.y; az += ww * v.z; aw += ww * v.w;
        }
        float4 o; o.x = ax; o.y = ay; o.z = az; o.w = aw;
        *(float4*)&cx[tok * 68 + d4] = o;
    }
    __syncthreads();

    const int tg = t & 7, og = t >> 3;
    const int t0 = tg << 2;                        // 4 tokens
    const int c0 = (h << 6) + (og << 1);           // 2 channels

    float acc[2][4];
    #pragma unroll
    for (int j = 0; j < 2; ++j)
        #pragma unroll
        for (int i = 0; i < 4; ++i) acc[j][i] = 0.f;

    for (int d0 = 0; d0 < 64; d0 += 4) {
        float xt[4][4];
        #pragma unroll
        for (int i = 0; i < 4; ++i) {
            float4 v = *(const float4*)&cx[(t0 + i) * 68 + d0];
            xt[i][0] = v.x; xt[i][1] = v.y; xt[i][2] = v.z; xt[i][3] = v.w;
        }
        #pragma unroll
        for (int j = 0; j < 2; ++j) {
            float4 w4 = *(const float4*)(Wo + (c0 + j) * 64 + d0);
            #pragma unroll
            for (int i = 0; i < 4; ++i)
                acc[j][i] += xt[i][0] * w4.x + xt[i][1] * w4.y
                           + xt[i][2] * w4.z + xt[i][3] * w4.w;
        }
    }

    #pragma unroll
    for (int j = 0; j < 2; ++j) {
        int c = c0 + j;
        float bias = bo[c];
        const float* ip = inpt + ((size_t)(b * 128 + c)) * 4096 + l0 + t0;
        float*       op = out  + ((size_t)(b * 128 + c)) * 4096 + l0 + t0;
        float4 iv = *(const float4*)ip;
        float4 ov;
        ov.x = iv.x + acc[j][0] + bias;
        ov.y = iv.y + acc[j][1] + bias;
        ov.z = iv.z + acc[j][2] + bias;
        ov.w = iv.w + acc[j][3] + bias;
        *(float4*)op = ov;
    }
}

// ---------------------------------------------------------------------------
extern "C" void kernel_launch(void* const* d_in, const int* in_sizes, int n_in,
                              void* d_out, int out_size, void* d_ws, size_t ws_size,
                              hipStream_t stream)
{
    const float* inpt = (const float*)d_in[0];
    const float* Wq   = (const float*)d_in[1];
    const float* bq   = (const float*)d_in[2];
    const float* Wk   = (const float*)d_in[3];
    const float* bk   = (const float*)d_in[4];
    const float* Wv   = (const float*)d_in[5];
    const float* bv   = (const float*)d_in[6];
    const float* Wo   = (const float*)d_in[7];
    const float* bo   = (const float*)d_in[8];
    float* out = (float*)d_out;

    char* ws = (char*)d_ws;
    const size_t MB = (size_t)1 << 20;
    __bf16* Qws  = (__bf16*)(ws + 0 * MB);
    __bf16* Kws  = (__bf16*)(ws + 2 * MB);
    __bf16* VTws = (__bf16*)(ws + 4 * MB);
    float*  Ops  = (float*)(ws + 6 * MB);          // SPLIT x 4MB = 16 MB
    float*  Mws  = (float*)(ws + 22 * MB);         // 256 KB
    float*  Lws  = (float*)(ws + 22 * MB + 256 * 1024);

    qkv_kernel<<<768, 256, 0, stream>>>(inpt, Wq, bq, Wk, bk, Wv, bv, Qws, Kws, VTws);
    attn_kernel<<<SPLIT * 256, 256, 0, stream>>>(Qws, Kws, VTws, Ops, Mws, Lws);
    outproj_kernel<<<1024, 256, 0, stream>>>(inpt, Ops, Mws, Lws, Wo, bo, out);
}

// Round 3
// 134.125 us; speedup vs baseline: 1.4632x; 1.1280x over previous
//
#include <hip/hip_runtime.h>
#include <hip/hip_bf16.h>

typedef __bf16 bf16x8 __attribute__((ext_vector_type(8)));
typedef __bf16 bf16x4 __attribute__((ext_vector_type(4)));
typedef short  s16x4  __attribute__((ext_vector_type(4)));
typedef float  f32x4  __attribute__((ext_vector_type(4)));

#define MFMA32(a, b, c) __builtin_amdgcn_mfma_f32_16x16x32_bf16((a), (b), (c), 0, 0, 0)
#define MFMA16K(a, b, c) __builtin_amdgcn_mfma_f32_16x16x16bf16_1k((a), (b), (c), 0, 0, 0)

#if __has_builtin(__builtin_amdgcn_exp2f)
#define EXP2F(x) __builtin_amdgcn_exp2f(x)
#else
#define EXP2F(x) __expf(0.6931471805599453f * (x))
#endif

// async global->LDS, 16B per lane. LDS dest must be wave-uniform base.
#define GL16(G, L)                                                            \
    __builtin_amdgcn_global_load_lds(                                         \
        (const __attribute__((address_space(1))) void*)(G),                   \
        (__attribute__((address_space(3))) void*)(L), 16, 0, 0)

#define SPLIT 4
// BS=4, C=128, L=4096, D=64. Q pre-scaled by 0.125*log2(e) so softmax runs in
// base-2 (exp2) throughout (attn and split-combine must agree on the base).
#define QSCALE 0.18033688011112042f

// ---------------------------------------------------------------------------
// Kernel 1: QKV projection, bf16 MFMA. grid = 1024 (b x 256 tiles of 16 tok).
// Q/K bf16 [b][l][64]; V bf16 transposed [b][d][4096] (scattered 2B stores --
// amortized by L2 write-combining within a block's 32B row chunks).
// ---------------------------------------------------------------------------
__global__ __launch_bounds__(256) void qkv_kernel(
    const float* __restrict__ inpt,
    const float* __restrict__ Wq, const float* __restrict__ bq,
    const float* __restrict__ Wk, const float* __restrict__ bk,
    const float* __restrict__ Wv, const float* __restrict__ bv,
    __bf16* __restrict__ Qws, __bf16* __restrict__ Kws, __bf16* __restrict__ VTws)
{
    __shared__ __align__(16) __bf16 xT[16 * 140];   // [tok][c], pad to 140
    const int bid = blockIdx.x;
    const int b   = bid >> 8;
    const int l0  = (bid & 255) << 4;               // 16 tokens
    const int t   = threadIdx.x;

    // stage x^T: thread (c = t>>1, half = t&1) loads 8 floats of row c
    {
        const int c = t >> 1, half = t & 1;
        const float* xin = inpt + ((size_t)(b * 128 + c)) * 4096 + l0 + half * 8;
        float4 v0 = *(const float4*)xin;
        float4 v1 = *(const float4*)(xin + 4);
        const int tok0 = half * 8;
        xT[(tok0 + 0) * 140 + c] = (__bf16)v0.x;
        xT[(tok0 + 1) * 140 + c] = (__bf16)v0.y;
        xT[(tok0 + 2) * 140 + c] = (__bf16)v0.z;
        xT[(tok0 + 3) * 140 + c] = (__bf16)v0.w;
        xT[(tok0 + 4) * 140 + c] = (__bf16)v1.x;
        xT[(tok0 + 5) * 140 + c] = (__bf16)v1.y;
        xT[(tok0 + 6) * 140 + c] = (__bf16)v1.z;
        xT[(tok0 + 7) * 140 + c] = (__bf16)v1.w;
    }
    __syncthreads();

    const int w    = t >> 6;
    const int lane = t & 63;
    const int quad = lane >> 4;
    const int l15  = lane & 15;

    f32x4 acc[3];
    #pragma unroll
    for (int j = 0; j < 3; ++j)
        #pragma unroll
        for (int r = 0; r < 4; ++r) acc[j][r] = 0.f;

    #pragma unroll
    for (int ks = 0; ks < 4; ++ks) {
        bf16x8 af = *(const bf16x8*)&xT[l15 * 140 + ks * 32 + quad * 8];
        #pragma unroll
        for (int j = 0; j < 3; ++j) {
            const int wn   = w * 3 + j;                 // n-tile 0..11
            const int msel = wn >> 2;                   // 0=Q 1=K 2=V
            const float* W = (msel == 0) ? Wq : ((msel == 1) ? Wk : Wv);
            const float* Wp = W + ((wn & 3) * 16 + l15) * 128 + ks * 32 + quad * 8;
            float4 wa = *(const float4*)Wp;
            float4 wb = *(const float4*)(Wp + 4);
            bf16x8 bf;
            bf[0] = (__bf16)wa.x; bf[1] = (__bf16)wa.y;
            bf[2] = (__bf16)wa.z; bf[3] = (__bf16)wa.w;
            bf[4] = (__bf16)wb.x; bf[5] = (__bf16)wb.y;
            bf[6] = (__bf16)wb.z; bf[7] = (__bf16)wb.w;
            acc[j] = MFMA32(af, bf, acc[j]);            // D[m=tok][n=out]
        }
    }

    // epilogue: D rows (quad*4+r) = token, col l15 = output within tile
    #pragma unroll
    for (int j = 0; j < 3; ++j) {
        const int wn   = w * 3 + j;
        const int msel = wn >> 2;
        const int o0   = (wn & 3) * 16;
        const float* bb = (msel == 0) ? bq : ((msel == 1) ? bk : bv);
        float bias = bb[o0 + l15];
        if (msel < 2) {
            __bf16* base = (msel == 0) ? Qws : Kws;
            const float scl = (msel == 0) ? QSCALE : 1.0f;
            #pragma unroll
            for (int r = 0; r < 4; ++r) {
                float v = (acc[j][r] + bias) * scl;
                base[((size_t)(b * 4096 + l0 + quad * 4 + r)) * 64 + o0 + l15] = (__bf16)v;
            }
        } else {
            const int d = o0 + l15;
            #pragma unroll
            for (int r = 0; r < 4; ++r) {
                float v = acc[j][r] + bias;
                VTws[((size_t)(b * 64 + d)) * 4096 + l0 + quad * 4 + r] = (__bf16)v;
            }
        }
    }
}

// ---------------------------------------------------------------------------
// Kernel 2: flash attention, split-K, double-buffered global_load_lds staging,
// XOR-swizzled LDS (conflict-free), in-register base-2 softmax, and PV via
// mfma 16x16x16bf16_1k whose B-layout == QK's C-layout (no P transpose at all).
// grid = SPLIT x 256; block = 64 q (wave owns 16), 16 k-tiles of 64 keys.
// ---------------------------------------------------------------------------
__global__ __launch_bounds__(256, 4) void attn_kernel(
    const __bf16* __restrict__ Qws, const __bf16* __restrict__ Kws,
    const __bf16* __restrict__ VTws,
    float* __restrict__ Ops, float* __restrict__ Mws, float* __restrict__ Lws)
{
    // buffer: slots of 16B. K: slots 0..511 = [key][chunk^(key&7)];
    //          V: slots 512..1023 = [d][chunk^(d&7)]
    __shared__ __align__(16) __bf16 sbuf[2][8192];   // 2 x 16 KB

    const int bid   = blockIdx.x;
    const int split = bid >> 8;
    const int qt    = bid & 255;
    const int b  = qt >> 6;
    const int l0 = (qt & 63) << 6;
    const int t    = threadIdx.x;
    const int w    = t >> 6;
    const int lane = t & 63;
    const int quad = lane >> 4;
    const int l15  = lane & 15;
    const int l7   = l15 & 7;

    // Q fragments (q = l15), pre-scaled by 0.125*log2e
    const __bf16* qptr = Qws + ((size_t)(b * 4096 + l0 + w * 16 + l15)) * 64 + quad * 8;
    bf16x8 qf0 = *(const bf16x8*)qptr;
    bf16x8 qf1 = *(const bf16x8*)(qptr + 32);

    f32x4 cfr[4];
    #pragma unroll
    for (int mt = 0; mt < 4; ++mt)
        #pragma unroll
        for (int r = 0; r < 4; ++r) cfr[mt][r] = 0.f;
    float m_run = -1e30f, l_run = 0.f;

    // per-thread staging source pointers (swizzled chunk)
    const uint4* Kg = (const uint4*)(Kws + ((size_t)b << 18));
    const uint4* Vg = (const uint4*)(VTws + ((size_t)b << 18));
    const int rw = t >> 3, cw = (t & 7) ^ ((t >> 3) & 7);
    const uint4* kp = Kg + rw * 8 + cw + split * 8192;      // keys advance 512/tile
    const uint4* vp = Vg + (size_t)rw * 512 + cw + split * 128;  // advance 8/tile

    union B4 { bf16x4 h; s16x4 s; };

    // prologue: stage tile 0 into buffer 0
    {
        __bf16* Bb = sbuf[0];
        GL16(kp,         Bb +        w * 512);
        GL16(kp + 256,   Bb + 2048 + w * 512);
        GL16(vp,         Bb + 4096 + w * 512);
        GL16(vp + 16384, Bb + 6144 + w * 512);
        kp += 512; vp += 8;
    }

    for (int kt = 0; kt < 16; ++kt) {
        const int cur = kt & 1;
        __syncthreads();               // drains vmcnt(0): current buffer ready
        if (kt < 15) {                 // prefetch next tile into other buffer
            __bf16* Bb = sbuf[cur ^ 1];
            GL16(kp,         Bb +        w * 512);
            GL16(kp + 256,   Bb + 2048 + w * 512);
            GL16(vp,         Bb + 4096 + w * 512);
            GL16(vp + 16384, Bb + 6144 + w * 512);
            kp += 512; vp += 8;
        }
        const __bf16* B = sbuf[cur];

        // ---- QK^T (A=K, B=Q): s[nt][r] = score(q=l15, key=16nt+4quad+r) ----
        f32x4 s[4];
        #pragma unroll
        for (int nt = 0; nt < 4; ++nt) {
            const int key = nt * 16 + l15;
            const int sw  = key * 8;
            const int kx  = key & 7;
            bf16x8 kf0 = *(const bf16x8*)&B[(sw + (quad ^ kx)) * 8];
            bf16x8 kf1 = *(const bf16x8*)&B[(sw + ((quad + 4) ^ kx)) * 8];
            f32x4 a = {0.f, 0.f, 0.f, 0.f};
            a = MFMA32(kf0, qf0, a);
            a = MFMA32(kf1, qf1, a);
            s[nt] = a;
        }

        // ---- online softmax (base 2), all in registers ----
        float mx = -1e30f;
        #pragma unroll
        for (int nt = 0; nt < 4; ++nt)
            #pragma unroll
            for (int r = 0; r < 4; ++r) mx = fmaxf(mx, s[nt][r]);
        mx = fmaxf(mx, __shfl_xor(mx, 16));
        mx = fmaxf(mx, __shfl_xor(mx, 32));
        float mnew  = fmaxf(m_run, mx);
        float alpha = EXP2F(m_run - mnew);
        m_run = mnew;

        float psum = 0.f;
        B4 pk[4];                       // P in C-layout == B-layout of 16x16x16
        #pragma unroll
        for (int nt = 0; nt < 4; ++nt) {
            #pragma unroll
            for (int r = 0; r < 4; ++r) {
                float p = EXP2F(s[nt][r] - mnew);
                psum += p;
                pk[nt].h[r] = (__bf16)p;
            }
        }
        psum += __shfl_xor(psum, 16);
        psum += __shfl_xor(psum, 32);
        l_run = l_run * alpha + psum;

        // ---- PV: ctx^T = ctx^T*alpha + V^T · P^T (16x16x16, no transpose) --
        #pragma unroll
        for (int mt = 0; mt < 4; ++mt)
            #pragma unroll
            for (int r = 0; r < 4; ++r) cfr[mt][r] *= alpha;

        const __bf16* Vb = B + 4096;    // V slots
        const int q2 = quad >> 1, q1 = (quad & 1) * 4;
        #pragma unroll
        for (int kc = 0; kc < 4; ++kc) {
            #pragma unroll
            for (int mt = 0; mt < 4; ++mt) {
                const int d  = mt * 16 + l15;
                const int cc = (2 * kc + q2) ^ l7;
                B4 vf;
                vf.h = *(const bf16x4*)&Vb[(d * 8 + cc) * 8 + q1];
                cfr[mt] = MFMA16K(vf.s, pk[kc].s, cfr[mt]);
            }
        }
    }

    // epilogue: unnormalized partial ctx + (m,l) per split. token = l15.
    const int l   = l0 + w * 16 + l15;
    const int row = (split * 4 + b) * 4096 + l;
    float* obase = Ops + (size_t)row * 64;
    #pragma unroll
    for (int mt = 0; mt < 4; ++mt)
        *(f32x4*)(obase + mt * 16 + quad * 4) = cfr[mt];
    if (quad == 0) { Mws[row] = m_run; Lws[row] = l_run; }
}

// ---------------------------------------------------------------------------
// Kernel 3: split-combine (base 2) + output projection (bf16 MFMA) + bias +
// residual. grid = 1024 (b x 256 tiles of 16 tokens); block does all 128 c.
// ---------------------------------------------------------------------------
__global__ __launch_bounds__(256) void outproj_kernel(
    const float* __restrict__ inpt,
    const float* __restrict__ Ops, const float* __restrict__ Mws,
    const float* __restrict__ Lws,
    const float* __restrict__ Wo, const float* __restrict__ bo,
    float* __restrict__ out)
{
    __shared__ __align__(16) __bf16 cx[16 * 72];    // combined ctx [tok][d]
    const int bid = blockIdx.x;
    const int b   = bid >> 8;
    const int l0  = (bid & 255) << 4;
    const int t   = threadIdx.x;

    // combine: thread (token = t>>4, d4 = (t&15)*4)
    {
        const int token = t >> 4, d4 = (t & 15) << 2;
        const int rowb  = b * 4096 + l0 + token;
        float m[SPLIT], ls[SPLIT], gmax = -1e30f;
        #pragma unroll
        for (int s = 0; s < SPLIT; ++s) {
            const int ro = s * 16384 + rowb;
            m[s] = Mws[ro]; ls[s] = Lws[ro];
            gmax = fmaxf(gmax, m[s]);
        }
        float denom = 0.f, e[SPLIT];
        #pragma unroll
        for (int s = 0; s < SPLIT; ++s) { e[s] = EXP2F(m[s] - gmax); denom += e[s] * ls[s]; }
        const float inv = 1.f / denom;
        float ax = 0.f, ay = 0.f, az = 0.f, aw = 0.f;
        #pragma unroll
        for (int s = 0; s < SPLIT; ++s) {
            const float4 v = *(const float4*)(Ops + ((size_t)(s * 16384 + rowb)) * 64 + d4);
            const float wgt = e[s] * inv;
            ax += wgt * v.x; ay += wgt * v.y; az += wgt * v.z; aw += wgt * v.w;
        }
        bf16x4 pv;
        pv[0] = (__bf16)ax; pv[1] = (__bf16)ay; pv[2] = (__bf16)az; pv[3] = (__bf16)aw;
        *(bf16x4*)&cx[token * 72 + d4] = pv;
    }
    __syncthreads();

    const int w    = t >> 6;
    const int lane = t & 63;
    const int quad = lane >> 4;
    const int l15  = lane & 15;

    f32x4 acc[2];
    #pragma unroll
    for (int mi = 0; mi < 2; ++mi)
        #pragma unroll
        for (int r = 0; r < 4; ++r) acc[mi][r] = 0.f;

    #pragma unroll
    for (int ks = 0; ks < 2; ++ks) {
        bf16x8 bfrag = *(const bf16x8*)&cx[l15 * 72 + ks * 32 + quad * 8];  // B[n=tok][k=d]
        #pragma unroll
        for (int mi = 0; mi < 2; ++mi) {
            const int crow = (w * 2 + mi) * 16 + l15;
            const float* Wp = Wo + crow * 64 + ks * 32 + quad * 8;
            float4 wa = *(const float4*)Wp;
            float4 wb = *(const float4*)(Wp + 4);
            bf16x8 afrag;
            afrag[0] = (__bf16)wa.x; afrag[1] = (__bf16)wa.y;
            afrag[2] = (__bf16)wa.z; afrag[3] = (__bf16)wa.w;
            afrag[4] = (__bf16)wb.x; afrag[5] = (__bf16)wb.y;
            afrag[6] = (__bf16)wb.z; afrag[7] = (__bf16)wb.w;
            acc[mi] = MFMA32(afrag, bfrag, acc[mi]);     // D[m=c][n=tok]
        }
    }

    // epilogue: rows (quad*4+r) = c offset, col l15 = token
    #pragma unroll
    for (int mi = 0; mi < 2; ++mi) {
        #pragma unroll
        for (int r = 0; r < 4; ++r) {
            const int c = (w * 2 + mi) * 16 + quad * 4 + r;
            const size_t addr = ((size_t)(b * 128 + c)) * 4096 + l0 + l15;
            out[addr] = inpt[addr] + bo[c] + acc[mi][r];
        }
    }
}

// ---------------------------------------------------------------------------
extern "C" void kernel_launch(void* const* d_in, const int* in_sizes, int n_in,
                              void* d_out, int out_size, void* d_ws, size_t ws_size,
                              hipStream_t stream)
{
    const float* inpt = (const float*)d_in[0];
    const float* Wq   = (const float*)d_in[1];
    const float* bq   = (const float*)d_in[2];
    const float* Wk   = (const float*)d_in[3];
    const float* bk   = (const float*)d_in[4];
    const float* Wv   = (const float*)d_in[5];
    const float* bv   = (const float*)d_in[6];
    const float* Wo   = (const float*)d_in[7];
    const float* bo   = (const float*)d_in[8];
    float* out = (float*)d_out;

    char* ws = (char*)d_ws;
    const size_t MB = (size_t)1 << 20;
    __bf16* Qws  = (__bf16*)(ws + 0 * MB);
    __bf16* Kws  = (__bf16*)(ws + 2 * MB);
    __bf16* VTws = (__bf16*)(ws + 4 * MB);
    float*  Ops  = (float*)(ws + 6 * MB);          // SPLIT x 4MB = 16 MB
    float*  Mws  = (float*)(ws + 22 * MB);         // 256 KB
    float*  Lws  = (float*)(ws + 22 * MB + 256 * 1024);

    qkv_kernel<<<1024, 256, 0, stream>>>(inpt, Wq, bq, Wk, bk, Wv, bv, Qws, Kws, VTws);
    attn_kernel<<<SPLIT * 256, 256, 0, stream>>>(Qws, Kws, VTws, Ops, Mws, Lws);
    outproj_kernel<<<1024, 256, 0, stream>>>(inpt, Ops, Mws, Lws, Wo, bo, out);
}